// Round 7
// baseline (201.846 us; speedup 1.0000x reference)
//
#include <hip/hip_runtime.h>

// GQA block. B=2, T=2048, C=1024, H=16, KV=8 (GROUP=2), D=64.
// Round 7: plain bf16 (1-product) MFMA everywhere, fp32 accumulate.
//  - gemm64: 128x64 tile, BK=64, DOUBLE-BUFFERED staging (one barrier/iter).
//  - attn5: 128-thread blocks, 2 waves, 64 q per wave (frag reads amortized
//    2x vs round 6), fixed m=0 softmax, double-buffered K/V, P via LDS.

#define SEQ    2048
#define CDIM   1024
#define KVDIM  512
#define SCL2E  0.18033688011112042f   // 0.125 * log2(e)

typedef __attribute__((ext_vector_type(8))) short   bf16x8;
typedef __attribute__((ext_vector_type(4))) float   f32x4;
typedef unsigned short ushort_t;

__device__ __forceinline__ ushort_t f2bf(float f) {
    unsigned u = __float_as_uint(f);
    u += 0x7FFFu + ((u >> 16) & 1u);
    return (ushort_t)(u >> 16);
}
__device__ __forceinline__ float bf2f(ushort_t h) {
    return __uint_as_float(((unsigned)h) << 16);
}
__device__ __forceinline__ void load_lds16(const void* g, void* l) {
    __builtin_amdgcn_global_load_lds(
        (const __attribute__((address_space(1))) void*)g,
        (__attribute__((address_space(3))) void*)l, 16, 0, 0);
}

// ---------------------------------------------------------------------------
// all five inputs -> bf16 hi, one launch. grid 7168 x 256 (exact).
// ---------------------------------------------------------------------------
__global__ __launch_bounds__(256) void cvt_bf16(
    const float* __restrict__ x,  const float* __restrict__ wq,
    const float* __restrict__ wk, const float* __restrict__ wv,
    const float* __restrict__ wp,
    ushort_t* __restrict__ xh,  ushort_t* __restrict__ wqh,
    ushort_t* __restrict__ wkh, ushort_t* __restrict__ wvh,
    ushort_t* __restrict__ wph)
{
    const int i = blockIdx.x * 256 + threadIdx.x;
    const float* src; ushort_t* dst; int off;
    if (i < 1048576)      { src = x;  dst = xh;  off = i; }
    else if (i < 1310720) { src = wq; dst = wqh; off = i - 1048576; }
    else if (i < 1441792) { src = wk; dst = wkh; off = i - 1310720; }
    else if (i < 1572864) { src = wv; dst = wvh; off = i - 1441792; }
    else                  { src = wp; dst = wph; off = i - 1572864; }
    const float4 v = ((const float4*)src)[off];
    ushort4 h;
    h.x = f2bf(v.x); h.y = f2bf(v.y); h.z = f2bf(v.z); h.w = f2bf(v.w);
    ((ushort4*)dst)[off] = h;
}

// ---------------------------------------------------------------------------
// bf16 MFMA GEMM, C = A*B^T, 1 product. Tile 128(M) x 64(N), BK=64, 256 thr,
// double-buffered LDS staging with ONE barrier per K-iteration.
// Waves 2x2 over tile (64m x 32n each). LDS rows xor-swizzled in 16B chunks.
// Up to 3 fused outputs along N. epi: 0 = fp32; 3 = bf16 hi * scale.
// ---------------------------------------------------------------------------
__global__ __launch_bounds__(256, 3) void gemm64(
    const ushort_t* __restrict__ A, int K,
    const ushort_t* __restrict__ B1, void* __restrict__ C1, int N1, int epi1, float sc1,
    const ushort_t* __restrict__ B2, void* __restrict__ C2, int N2, int epi2, float sc2,
    const ushort_t* __restrict__ B3, void* __restrict__ C3, int N3, int epi3, float sc3)
{
    __shared__ ushort_t sA[2][128 * 64];   // 2 x 16 KB
    __shared__ ushort_t sB[2][64 * 64];    // 2 x 8 KB

    const int tid = threadIdx.x, wv = tid >> 6, lane = tid & 63;
    const int lm = lane & 15, quad = lane >> 4;
    const int m0 = blockIdx.y * 128;

    const int t1 = N1 >> 6, t2 = N2 >> 6;
    const int bx = blockIdx.x;
    const ushort_t* B; void* Cv; int n0, Nout, epi; float sc;
    if (bx < t1)           { B = B1; Cv = C1; Nout = N1; epi = epi1; sc = sc1; n0 = bx * 64; }
    else if (bx < t1 + t2) { B = B2; Cv = C2; Nout = N2; epi = epi2; sc = sc2; n0 = (bx - t1) * 64; }
    else                   { B = B3; Cv = C3; Nout = N3; epi = epi3; sc = sc3; n0 = (bx - t1 - t2) * 64; }

    const int mh = wv >> 1, nh = wv & 1;
    const int srow = lane >> 3;
    const int scol = ((lane & 7) ^ ((lane >> 3) & 7)) * 8;

    f32x4 acc[4][2] = {};

    // preload k-tile 0 into buffer 0
    #pragma unroll
    for (int i = 0; i < 6; ++i) {
        const int g = wv * 6 + i;           // 0..15 A groups, 16..23 B groups
        if (g < 16)
            load_lds16(A + (size_t)(m0 + g * 8 + srow) * K + scol, &sA[0][g * 512]);
        else
            load_lds16(B + (size_t)(n0 + (g - 16) * 8 + srow) * K + scol, &sB[0][(g - 16) * 512]);
    }

    const int iters = K >> 6;
    for (int it = 0; it < iters; ++it) {
        const int cur = it & 1;
        __syncthreads();    // tile `it` landed; everyone done with buf cur^1

        if (it + 1 < iters) {
            const int k1 = (it + 1) * 64;
            #pragma unroll
            for (int i = 0; i < 6; ++i) {
                const int g = wv * 6 + i;
                if (g < 16)
                    load_lds16(A + (size_t)(m0 + g * 8 + srow) * K + k1 + scol, &sA[cur ^ 1][g * 512]);
                else
                    load_lds16(B + (size_t)(n0 + (g - 16) * 8 + srow) * K + k1 + scol, &sB[cur ^ 1][(g - 16) * 512]);
            }
        }

        #pragma unroll
        for (int ks = 0; ks < 2; ++ks) {
            const int co = ((ks * 4 + quad) ^ (lm & 7)) * 8;
            bf16x8 a[4], b[2];
            #pragma unroll
            for (int mt = 0; mt < 4; ++mt)
                a[mt] = *(const bf16x8*)&sA[cur][(mh * 64 + mt * 16 + lm) * 64 + co];
            #pragma unroll
            for (int nt = 0; nt < 2; ++nt)
                b[nt] = *(const bf16x8*)&sB[cur][(nh * 32 + nt * 16 + lm) * 64 + co];
            #pragma unroll
            for (int mt = 0; mt < 4; ++mt)
                #pragma unroll
                for (int nt = 0; nt < 2; ++nt)
                    acc[mt][nt] = __builtin_amdgcn_mfma_f32_16x16x32_bf16(a[mt], b[nt], acc[mt][nt], 0, 0, 0);
        }
    }

    // C/D: row = m + quad*4 + reg, col = n + lm
    if (epi == 0) {
        float* C = (float*)Cv;
        #pragma unroll
        for (int mt = 0; mt < 4; ++mt)
            #pragma unroll
            for (int nt = 0; nt < 2; ++nt)
                #pragma unroll
                for (int r = 0; r < 4; ++r)
                    C[(size_t)(m0 + mh * 64 + mt * 16 + quad * 4 + r) * Nout + n0 + nh * 32 + nt * 16 + lm]
                        = acc[mt][nt][r];
    } else {
        ushort_t* C = (ushort_t*)Cv;
        #pragma unroll
        for (int mt = 0; mt < 4; ++mt)
            #pragma unroll
            for (int nt = 0; nt < 2; ++nt)
                #pragma unroll
                for (int r = 0; r < 4; ++r)
                    C[(size_t)(m0 + mh * 64 + mt * 16 + quad * 4 + r) * Nout + n0 + nh * 32 + nt * 16 + lm]
                        = f2bf(acc[mt][nt][r] * sc);
    }
}

// ---------------------------------------------------------------------------
// v (fp32, [b*2048+t][512]) -> vth (bf16, [(b*8+kv)*64 + d][2048])
// ---------------------------------------------------------------------------
__global__ __launch_bounds__(256) void vtrans_kernel(
    const float* __restrict__ v, ushort_t* __restrict__ vt)
{
    __shared__ float tile[64][65];
    const int t0  = blockIdx.x * 64;
    const int bkv = blockIdx.y;
    const int r   = threadIdx.x >> 2;
    const int c0  = (threadIdx.x & 3) * 16;

    const float* src = v + (size_t)((bkv >> 3) * SEQ + t0 + r) * KVDIM + (bkv & 7) * 64 + c0;
    #pragma unroll
    for (int i = 0; i < 4; ++i) {
        const float4 f = *(const float4*)(src + i * 4);
        tile[r][c0 + i*4 + 0] = f.x;
        tile[r][c0 + i*4 + 1] = f.y;
        tile[r][c0 + i*4 + 2] = f.z;
        tile[r][c0 + i*4 + 3] = f.w;
    }
    __syncthreads();
    ushort_t* dst = vt + (size_t)(bkv * 64 + r) * SEQ + t0 + c0;
    #pragma unroll
    for (int i = 0; i < 4; ++i) {
        ushort4 u;
        u.x = f2bf(tile[c0 + i*4 + 0][r]);
        u.y = f2bf(tile[c0 + i*4 + 1][r]);
        u.z = f2bf(tile[c0 + i*4 + 2][r]);
        u.w = f2bf(tile[c0 + i*4 + 3][r]);
        *(ushort4*)(dst + i * 4) = u;
    }
}

// ---------------------------------------------------------------------------
// MFMA flash attention, fixed m=0 softmax, all-bf16 operands, fp32 acc.
// grid (SEQ/128, B*NHEAD), 128 threads (2 waves). Wave w handles q rows
// [t0 + w*64, +64) as 4 groups of 16 (Q-hi B-frags in registers, pre-scaled
// by 0.125*log2e). Wave 0 stages K, wave 1 stages V; double-buffered,
// ONE barrier per K-tile. S^T = K Q^T (1 product); P = exp2(S^T) truncated
// to bf16 via v_perm -> per-wave LDS -> A-frags; O += P V (1 product).
// ---------------------------------------------------------------------------
__global__ __launch_bounds__(128, 2) void attn5(
    const ushort_t* __restrict__ Qh, const ushort_t* __restrict__ Kh,
    const ushort_t* __restrict__ Vth, ushort_t* __restrict__ Yh)
{
    __shared__ ushort_t sK[2][64 * 64];   // 2 x 8 KB
    __shared__ ushort_t sV[2][64 * 64];   // 2 x 8 KB
    __shared__ ushort_t sP[2][64 * 64];   // per-wave 8 KB P scratch

    const int tid = threadIdx.x, wv = tid >> 6, lane = tid & 63;
    const int lm = lane & 15, quad = lane >> 4;
    const int b = blockIdx.y >> 4, h = blockIdx.y & 15, kvh = h >> 1;
    const int t0 = blockIdx.x * 128, tq0 = t0 + wv * 64;

    // persistent Q B-frags: n = q = lm (per group), k = d = ks*32 + quad*8 + j
    bf16x8 qf[4][2];
    #pragma unroll
    for (int qg = 0; qg < 4; ++qg) {
        const size_t rb = (size_t)(b * SEQ + tq0 + qg * 16 + lm) * CDIM + h * 64;
        #pragma unroll
        for (int ks = 0; ks < 2; ++ks)
            qf[qg][ks] = *(const bf16x8*)(Qh + rb + ks * 32 + quad * 8);
    }

    const ushort_t* gK = Kh  + (size_t)b * SEQ * KVDIM + kvh * 64;
    const ushort_t* gV = Vth + (size_t)(b * 8 + kvh) * 64 * SEQ;
    ushort_t* pw = sP[wv];

    const int srow = lane >> 3;
    const int scol = ((lane & 7) ^ ((lane >> 3) & 7)) * 8;

    float l_r[4] = {};
    f32x4 O[4][4] = {};

    // preload K/V tile 0 into buffer 0
    if (wv == 0) {
        #pragma unroll
        for (int it = 0; it < 8; ++it)
            load_lds16(gK + (size_t)(it * 8 + srow) * KVDIM + scol, &sK[0][it * 512]);
    } else {
        #pragma unroll
        for (int it = 0; it < 8; ++it)
            load_lds16(gV + (size_t)(it * 8 + srow) * SEQ + scol, &sV[0][it * 512]);
    }

    for (int kt = 0; kt < SEQ / 64; ++kt) {
        const int cur = kt & 1;
        __syncthreads();    // tile kt landed; both waves done with buf cur^1

        if (kt + 1 < SEQ / 64) {
            const int s1 = (kt + 1) * 64;
            if (wv == 0) {
                #pragma unroll
                for (int it = 0; it < 8; ++it)
                    load_lds16(gK + (size_t)(s1 + it * 8 + srow) * KVDIM + scol,
                               &sK[cur ^ 1][it * 512]);
            } else {
                #pragma unroll
                for (int it = 0; it < 8; ++it)
                    load_lds16(gV + (size_t)(it * 8 + srow) * SEQ + s1 + scol,
                               &sV[cur ^ 1][it * 512]);
            }
        }

        // S^T = K Q^T : col = q = lm, row = s = sti*16 + quad*4 + r
        f32x4 st[4][4] = {};
        #pragma unroll
        for (int sti = 0; sti < 4; ++sti)
            #pragma unroll
            for (int ks = 0; ks < 2; ++ks) {
                const int off = (sti * 16 + lm) * 64 + (((ks * 4 + quad) ^ (lm & 7)) * 8);
                const bf16x8 kf = *(const bf16x8*)&sK[cur][off];
                #pragma unroll
                for (int qg = 0; qg < 4; ++qg)
                    st[qg][sti] = __builtin_amdgcn_mfma_f32_16x16x32_bf16(kf, qf[qg][ks], st[qg][sti], 0, 0, 0);
            }

        // P = exp2(S'), accumulate l, pack bf16 (truncate via v_perm) -> LDS
        #pragma unroll
        for (int qg = 0; qg < 4; ++qg)
            #pragma unroll
            for (int sti = 0; sti < 4; ++sti) {
                const float p0 = __builtin_amdgcn_exp2f(st[qg][sti][0]);
                const float p1 = __builtin_amdgcn_exp2f(st[qg][sti][1]);
                const float p2 = __builtin_amdgcn_exp2f(st[qg][sti][2]);
                const float p3 = __builtin_amdgcn_exp2f(st[qg][sti][3]);
                l_r[qg] += (p0 + p1) + (p2 + p3);
                uint2 u;
                u.x = __builtin_amdgcn_perm(__float_as_uint(p1), __float_as_uint(p0), 0x07060302u);
                u.y = __builtin_amdgcn_perm(__float_as_uint(p3), __float_as_uint(p2), 0x07060302u);
                const int off = (qg * 16 + lm) * 64
                              + (((sti * 2 + (quad >> 1)) ^ (lm & 7)) * 8) + (quad & 1) * 4;
                *(uint2*)&pw[off] = u;
            }
        __asm__ volatile("s_waitcnt lgkmcnt(0)" ::: "memory");

        // O += P V : A = P (m=q), B = V^T (n=d), k = s
        #pragma unroll
        for (int ks = 0; ks < 2; ++ks) {
            const int co = ((ks * 4 + quad) ^ (lm & 7)) * 8;
            bf16x8 pa[4];
            #pragma unroll
            for (int qg = 0; qg < 4; ++qg)
                pa[qg] = *(const bf16x8*)&pw[(qg * 16 + lm) * 64 + co];
            #pragma unroll
            for (int dt = 0; dt < 4; ++dt) {
                const bf16x8 vt = *(const bf16x8*)&sV[cur][(dt * 16 + lm) * 64 + co];
                #pragma unroll
                for (int qg = 0; qg < 4; ++qg)
                    O[qg][dt] = __builtin_amdgcn_mfma_f32_16x16x32_bf16(pa[qg], vt, O[qg][dt], 0, 0, 0);
            }
        }
    }

    // l: reduce across quads (disjoint s quarters)
    #pragma unroll
    for (int qg = 0; qg < 4; ++qg) {
        l_r[qg] += __shfl_xor(l_r[qg], 16);
        l_r[qg] += __shfl_xor(l_r[qg], 32);
    }
    // O C-layout: col = d = dt*16 + lm, row = q = qg*16 + quad*4 + r
    #pragma unroll
    for (int qg = 0; qg < 4; ++qg)
        #pragma unroll
        for (int r = 0; r < 4; ++r) {
            const float lq = __shfl(l_r[qg], (lane & 48) | (quad * 4 + r));
            const float inv = 1.0f / lq;
            const int t = tq0 + qg * 16 + quad * 4 + r;
            const size_t rowb = (size_t)(b * SEQ + t) * CDIM + h * 64;
            #pragma unroll
            for (int dt = 0; dt < 4; ++dt)
                Yh[rowb + dt * 16 + lm] = f2bf(O[qg][dt][r] * inv);
        }
}

// ---------------------------------------------------------------------------
extern "C" void kernel_launch(void* const* d_in, const int* in_sizes, int n_in,
                              void* d_out, int out_size, void* d_ws, size_t ws_size,
                              hipStream_t stream)
{
    const float* x     = (const float*)d_in[0];
    const float* Wq    = (const float*)d_in[1];
    const float* Wk    = (const float*)d_in[2];
    const float* Wv    = (const float*)d_in[3];
    const float* Wproj = (const float*)d_in[4];
    float* out = (float*)d_out;

    const int M = 2 * SEQ;   // 4096

    char* p = (char*)d_ws;
    ushort_t* xh   = (ushort_t*)p; p += (size_t)M * CDIM * 2;        // 8 MB, reused as yh
    ushort_t* wqh  = (ushort_t*)p; p += (size_t)CDIM * CDIM * 2;     // 2 MB
    ushort_t* wkh  = (ushort_t*)p; p += (size_t)KVDIM * CDIM * 2;    // 1 MB
    ushort_t* wvh  = (ushort_t*)p; p += (size_t)KVDIM * CDIM * 2;    // 1 MB
    ushort_t* wph  = (ushort_t*)p; p += (size_t)CDIM * CDIM * 2;     // 2 MB
    ushort_t* qh   = (ushort_t*)p; p += (size_t)M * CDIM * 2;        // 8 MB
    ushort_t* kh   = (ushort_t*)p; p += (size_t)M * KVDIM * 2;       // 4 MB
    float*    vbuf = (float*)p;    p += (size_t)M * KVDIM * 4;       // 8 MB
    ushort_t* vth  = (ushort_t*)p; p += (size_t)M * KVDIM * 2;       // 4 MB
    ushort_t* yh = xh;   // x no longer needed once qkv GEMM is done

    dim3 blk(256);

    cvt_bf16<<<dim3(7168), blk, 0, stream>>>(
        x, Wq, Wk, Wv, Wproj, xh, wqh, wkh, wvh, wph);

    // fused q/k/v projections: q bf16*SCL2E, k bf16, v fp32
    gemm64<<<dim3(32, 32), blk, 0, stream>>>(
        xh, CDIM,
        wqh, qh,   CDIM,  3, SCL2E,
        wkh, kh,   KVDIM, 3, 1.0f,
        wvh, vbuf, KVDIM, 0, 1.0f);

    vtrans_kernel<<<dim3(SEQ / 64, 16), blk, 0, stream>>>(vbuf, vth);

    attn5<<<dim3(SEQ / 128, 32), dim3(128), 0, stream>>>(qh, kh, vth, yh);

    gemm64<<<dim3(16, 32), blk, 0, stream>>>(
        yh, CDIM,
        wph, out, CDIM, 0, 1.0f,
        nullptr, nullptr, 0, 0, 1.0f,
        nullptr, nullptr, 0, 0, 1.0f);
}

// Round 8
// 174.190 us; speedup vs baseline: 1.1588x; 1.1588x over previous
//
#include <hip/hip_runtime.h>

// GQA block. B=2, T=2048, C=1024, H=16, KV=8 (GROUP=2), D=64.
// Round 8: revert attn to round-6 attn4 (best known: 55 us, 256-thr blocks).
// GEMMs -> 128x128 tile, BK=64, double-buffered, one barrier/iter
// (32 MFMA per 192 DS-cyc per wave-iter vs 16 for the old 128x64 tile).

#define SEQ    2048
#define CDIM   1024
#define KVDIM  512
#define SCL2E  0.18033688011112042f   // 0.125 * log2(e)

typedef __attribute__((ext_vector_type(8))) short   bf16x8;
typedef __attribute__((ext_vector_type(4))) float   f32x4;
typedef unsigned short ushort_t;

__device__ __forceinline__ ushort_t f2bf(float f) {
    unsigned u = __float_as_uint(f);
    u += 0x7FFFu + ((u >> 16) & 1u);
    return (ushort_t)(u >> 16);
}
__device__ __forceinline__ float bf2f(ushort_t h) {
    return __uint_as_float(((unsigned)h) << 16);
}
__device__ __forceinline__ void load_lds16(const void* g, void* l) {
    __builtin_amdgcn_global_load_lds(
        (const __attribute__((address_space(1))) void*)g,
        (__attribute__((address_space(3))) void*)l, 16, 0, 0);
}

// ---------------------------------------------------------------------------
// all five inputs -> bf16 hi, one launch. grid 7168 x 256 (exact).
// ---------------------------------------------------------------------------
__global__ __launch_bounds__(256) void cvt_bf16(
    const float* __restrict__ x,  const float* __restrict__ wq,
    const float* __restrict__ wk, const float* __restrict__ wv,
    const float* __restrict__ wp,
    ushort_t* __restrict__ xh,  ushort_t* __restrict__ wqh,
    ushort_t* __restrict__ wkh, ushort_t* __restrict__ wvh,
    ushort_t* __restrict__ wph)
{
    const int i = blockIdx.x * 256 + threadIdx.x;
    const float* src; ushort_t* dst; int off;
    if (i < 1048576)      { src = x;  dst = xh;  off = i; }
    else if (i < 1310720) { src = wq; dst = wqh; off = i - 1048576; }
    else if (i < 1441792) { src = wk; dst = wkh; off = i - 1310720; }
    else if (i < 1572864) { src = wv; dst = wvh; off = i - 1441792; }
    else                  { src = wp; dst = wph; off = i - 1572864; }
    const float4 v = ((const float4*)src)[off];
    ushort4 h;
    h.x = f2bf(v.x); h.y = f2bf(v.y); h.z = f2bf(v.z); h.w = f2bf(v.w);
    ((ushort4*)dst)[off] = h;
}

// ---------------------------------------------------------------------------
// bf16 MFMA GEMM, C = A*B^T, 1 product. Tile 128(M) x 128(N), BK=64, 256 thr,
// DOUBLE-BUFFERED staging (one barrier per K-iter). Waves 2x2 over the tile,
// each computing a 64x64 quadrant (4x4 of 16x16, 32 MFMA/iter).
// LDS rows (64 k) xor-swizzled in 16B chunks (inverse on global src side).
// Up to 3 fused outputs along N. epi: 0 = fp32; 3 = bf16 hi * scale.
// ---------------------------------------------------------------------------
__global__ __launch_bounds__(256, 2) void gemm128db(
    const ushort_t* __restrict__ A, int K,
    const ushort_t* __restrict__ B1, void* __restrict__ C1, int N1, int epi1, float sc1,
    const ushort_t* __restrict__ B2, void* __restrict__ C2, int N2, int epi2, float sc2,
    const ushort_t* __restrict__ B3, void* __restrict__ C3, int N3, int epi3, float sc3)
{
    __shared__ ushort_t sA[2][128 * 64];   // 2 x 16 KB
    __shared__ ushort_t sB[2][128 * 64];   // 2 x 16 KB

    const int tid = threadIdx.x, wv = tid >> 6, lane = tid & 63;
    const int lm = lane & 15, quad = lane >> 4;
    const int m0 = blockIdx.y * 128;

    const int t1 = N1 >> 7, t2 = N2 >> 7;
    const int bx = blockIdx.x;
    const ushort_t* B; void* Cv; int n0, Nout, epi; float sc;
    if (bx < t1)           { B = B1; Cv = C1; Nout = N1; epi = epi1; sc = sc1; n0 = bx * 128; }
    else if (bx < t1 + t2) { B = B2; Cv = C2; Nout = N2; epi = epi2; sc = sc2; n0 = (bx - t1) * 128; }
    else                   { B = B3; Cv = C3; Nout = N3; epi = epi3; sc = sc3; n0 = (bx - t1 - t2) * 128; }

    const int mh = wv >> 1, nh = wv & 1;
    const int srow = lane >> 3;
    const int scol = ((lane & 7) ^ ((lane >> 3) & 7)) * 8;

    f32x4 acc[4][4] = {};

    // preload k-tile 0 into buffer 0 (wave w stages groups w*8 .. w*8+7)
    #pragma unroll
    for (int i = 0; i < 8; ++i) {
        const int g = wv * 8 + i;           // 0..15 A groups, 16..31 B groups
        if (g < 16)
            load_lds16(A + (size_t)(m0 + g * 8 + srow) * K + scol, &sA[0][g * 512]);
        else
            load_lds16(B + (size_t)(n0 + (g - 16) * 8 + srow) * K + scol, &sB[0][(g - 16) * 512]);
    }

    const int iters = K >> 6;
    for (int it = 0; it < iters; ++it) {
        const int cur = it & 1;
        __syncthreads();    // tile `it` landed; everyone done with buf cur^1

        if (it + 1 < iters) {
            const int k1 = (it + 1) * 64;
            #pragma unroll
            for (int i = 0; i < 8; ++i) {
                const int g = wv * 8 + i;
                if (g < 16)
                    load_lds16(A + (size_t)(m0 + g * 8 + srow) * K + k1 + scol, &sA[cur ^ 1][g * 512]);
                else
                    load_lds16(B + (size_t)(n0 + (g - 16) * 8 + srow) * K + k1 + scol, &sB[cur ^ 1][(g - 16) * 512]);
            }
        }

        #pragma unroll
        for (int ks = 0; ks < 2; ++ks) {
            const int co = ((ks * 4 + quad) ^ (lm & 7)) * 8;
            bf16x8 a[4], b[4];
            #pragma unroll
            for (int mt = 0; mt < 4; ++mt)
                a[mt] = *(const bf16x8*)&sA[cur][(mh * 64 + mt * 16 + lm) * 64 + co];
            #pragma unroll
            for (int nt = 0; nt < 4; ++nt)
                b[nt] = *(const bf16x8*)&sB[cur][(nh * 64 + nt * 16 + lm) * 64 + co];
            #pragma unroll
            for (int mt = 0; mt < 4; ++mt)
                #pragma unroll
                for (int nt = 0; nt < 4; ++nt)
                    acc[mt][nt] = __builtin_amdgcn_mfma_f32_16x16x32_bf16(a[mt], b[nt], acc[mt][nt], 0, 0, 0);
        }
    }

    // C/D: row = m + quad*4 + reg, col = n + lm
    if (epi == 0) {
        float* C = (float*)Cv;
        #pragma unroll
        for (int mt = 0; mt < 4; ++mt)
            #pragma unroll
            for (int nt = 0; nt < 4; ++nt)
                #pragma unroll
                for (int r = 0; r < 4; ++r)
                    C[(size_t)(m0 + mh * 64 + mt * 16 + quad * 4 + r) * Nout + n0 + nh * 64 + nt * 16 + lm]
                        = acc[mt][nt][r];
    } else {
        ushort_t* C = (ushort_t*)Cv;
        #pragma unroll
        for (int mt = 0; mt < 4; ++mt)
            #pragma unroll
            for (int nt = 0; nt < 4; ++nt)
                #pragma unroll
                for (int r = 0; r < 4; ++r)
                    C[(size_t)(m0 + mh * 64 + mt * 16 + quad * 4 + r) * Nout + n0 + nh * 64 + nt * 16 + lm]
                        = f2bf(acc[mt][nt][r] * sc);
    }
}

// ---------------------------------------------------------------------------
// v (fp32, [b*2048+t][512]) -> vth (bf16, [(b*8+kv)*64 + d][2048])
// ---------------------------------------------------------------------------
__global__ __launch_bounds__(256) void vtrans_kernel(
    const float* __restrict__ v, ushort_t* __restrict__ vt)
{
    __shared__ float tile[64][65];
    const int t0  = blockIdx.x * 64;
    const int bkv = blockIdx.y;
    const int r   = threadIdx.x >> 2;
    const int c0  = (threadIdx.x & 3) * 16;

    const float* src = v + (size_t)((bkv >> 3) * SEQ + t0 + r) * KVDIM + (bkv & 7) * 64 + c0;
    #pragma unroll
    for (int i = 0; i < 4; ++i) {
        const float4 f = *(const float4*)(src + i * 4);
        tile[r][c0 + i*4 + 0] = f.x;
        tile[r][c0 + i*4 + 1] = f.y;
        tile[r][c0 + i*4 + 2] = f.z;
        tile[r][c0 + i*4 + 3] = f.w;
    }
    __syncthreads();
    ushort_t* dst = vt + (size_t)(bkv * 64 + r) * SEQ + t0 + c0;
    #pragma unroll
    for (int i = 0; i < 4; ++i) {
        ushort4 u;
        u.x = f2bf(tile[c0 + i*4 + 0][r]);
        u.y = f2bf(tile[c0 + i*4 + 1][r]);
        u.z = f2bf(tile[c0 + i*4 + 2][r]);
        u.w = f2bf(tile[c0 + i*4 + 3][r]);
        *(ushort4*)(dst + i * 4) = u;
    }
}

// ---------------------------------------------------------------------------
// MFMA flash attention (round-6 attn4, verbatim). Fixed m=0 softmax,
// all-bf16 operands, fp32 acc. grid (SEQ/128, B*NHEAD), 256 threads.
// ---------------------------------------------------------------------------
__global__ __launch_bounds__(256, 2) void attn4(
    const ushort_t* __restrict__ Qh, const ushort_t* __restrict__ Kh,
    const ushort_t* __restrict__ Vth, ushort_t* __restrict__ Yh)
{
    __shared__ ushort_t sK[2][64 * 64];
    __shared__ ushort_t sV[2][64 * 64];
    __shared__ ushort_t sP[4 * 2048];

    const int tid = threadIdx.x, wv = tid >> 6, lane = tid & 63;
    const int lm = lane & 15, quad = lane >> 4;
    const int b = blockIdx.y >> 4, h = blockIdx.y & 15, kvh = h >> 1;
    const int t0 = blockIdx.x * 128, tq0 = t0 + wv * 32;

    bf16x8 qh[2][2];
    #pragma unroll
    for (int qg = 0; qg < 2; ++qg) {
        const size_t rb = (size_t)(b * SEQ + tq0 + qg * 16 + lm) * CDIM + h * 64;
        #pragma unroll
        for (int ks = 0; ks < 2; ++ks)
            qh[qg][ks] = *(const bf16x8*)(Qh + rb + ks * 32 + quad * 8);
    }

    const ushort_t* gK = Kh  + (size_t)b * SEQ * KVDIM + kvh * 64;
    const ushort_t* gV = Vth + (size_t)(b * 8 + kvh) * 64 * SEQ;
    ushort_t* pw = sP + wv * 2048;

    const int sit  = (wv & 1) * 4;
    const int srow = lane >> 3;
    const int scol = ((lane & 7) ^ ((lane >> 3) & 7)) * 8;

    float l_r[2] = {0.0f, 0.0f};
    f32x4 O[2][4] = {};

    if (wv < 2) {
        #pragma unroll
        for (int it = 0; it < 4; ++it)
            load_lds16(gK + (size_t)((sit + it) * 8 + srow) * KVDIM + scol,
                       &sK[0][(sit + it) * 512]);
    } else {
        #pragma unroll
        for (int it = 0; it < 4; ++it)
            load_lds16(gV + (size_t)((sit + it) * 8 + srow) * SEQ + scol,
                       &sV[0][(sit + it) * 512]);
    }

    for (int kt = 0; kt < SEQ / 64; ++kt) {
        const int cur = kt & 1;
        __syncthreads();

        if (kt + 1 < SEQ / 64) {
            const int s1 = (kt + 1) * 64;
            if (wv < 2) {
                #pragma unroll
                for (int it = 0; it < 4; ++it)
                    load_lds16(gK + (size_t)(s1 + (sit + it) * 8 + srow) * KVDIM + scol,
                               &sK[cur ^ 1][(sit + it) * 512]);
            } else {
                #pragma unroll
                for (int it = 0; it < 4; ++it)
                    load_lds16(gV + (size_t)((sit + it) * 8 + srow) * SEQ + s1 + scol,
                               &sV[cur ^ 1][(sit + it) * 512]);
            }
        }

        f32x4 st[2][4] = {};
        #pragma unroll
        for (int sti = 0; sti < 4; ++sti)
            #pragma unroll
            for (int ks = 0; ks < 2; ++ks) {
                const int off = (sti * 16 + lm) * 64 + (((ks * 4 + quad) ^ (lm & 7)) * 8);
                const bf16x8 kf = *(const bf16x8*)&sK[cur][off];
                #pragma unroll
                for (int qg = 0; qg < 2; ++qg)
                    st[qg][sti] = __builtin_amdgcn_mfma_f32_16x16x32_bf16(kf, qh[qg][ks], st[qg][sti], 0, 0, 0);
            }

        #pragma unroll
        for (int qg = 0; qg < 2; ++qg)
            #pragma unroll
            for (int sti = 0; sti < 4; ++sti) {
                const float p0 = __builtin_amdgcn_exp2f(st[qg][sti][0]);
                const float p1 = __builtin_amdgcn_exp2f(st[qg][sti][1]);
                const float p2 = __builtin_amdgcn_exp2f(st[qg][sti][2]);
                const float p3 = __builtin_amdgcn_exp2f(st[qg][sti][3]);
                l_r[qg] += (p0 + p1) + (p2 + p3);
                uint2 u;
                u.x = __builtin_amdgcn_perm(__float_as_uint(p1), __float_as_uint(p0), 0x07060302u);
                u.y = __builtin_amdgcn_perm(__float_as_uint(p3), __float_as_uint(p2), 0x07060302u);
                const int off = (qg * 16 + lm) * 64
                              + (((sti * 2 + (quad >> 1)) ^ (lm & 7)) * 8) + (quad & 1) * 4;
                *(uint2*)&pw[off] = u;
            }
        __asm__ volatile("s_waitcnt lgkmcnt(0)" ::: "memory");

        #pragma unroll
        for (int ks = 0; ks < 2; ++ks) {
            const int co = ((ks * 4 + quad) ^ (lm & 7)) * 8;
            bf16x8 pa[2];
            #pragma unroll
            for (int qg = 0; qg < 2; ++qg)
                pa[qg] = *(const bf16x8*)&pw[(qg * 16 + lm) * 64 + co];
            #pragma unroll
            for (int dt = 0; dt < 4; ++dt) {
                const bf16x8 vt = *(const bf16x8*)&sV[cur][(dt * 16 + lm) * 64 + co];
                #pragma unroll
                for (int qg = 0; qg < 2; ++qg)
                    O[qg][dt] = __builtin_amdgcn_mfma_f32_16x16x32_bf16(pa[qg], vt, O[qg][dt], 0, 0, 0);
            }
        }
    }

    #pragma unroll
    for (int qg = 0; qg < 2; ++qg) {
        l_r[qg] += __shfl_xor(l_r[qg], 16);
        l_r[qg] += __shfl_xor(l_r[qg], 32);
    }
    #pragma unroll
    for (int qg = 0; qg < 2; ++qg)
        #pragma unroll
        for (int r = 0; r < 4; ++r) {
            const float lq = __shfl(l_r[qg], (lane & 48) | (quad * 4 + r));
            const float inv = 1.0f / lq;
            const int t = tq0 + qg * 16 + quad * 4 + r;
            const size_t rowb = (size_t)(b * SEQ + t) * CDIM + h * 64;
            #pragma unroll
            for (int dt = 0; dt < 4; ++dt)
                Yh[rowb + dt * 16 + lm] = f2bf(O[qg][dt][r] * inv);
        }
}

// ---------------------------------------------------------------------------
extern "C" void kernel_launch(void* const* d_in, const int* in_sizes, int n_in,
                              void* d_out, int out_size, void* d_ws, size_t ws_size,
                              hipStream_t stream)
{
    const float* x     = (const float*)d_in[0];
    const float* Wq    = (const float*)d_in[1];
    const float* Wk    = (const float*)d_in[2];
    const float* Wv    = (const float*)d_in[3];
    const float* Wproj = (const float*)d_in[4];
    float* out = (float*)d_out;

    const int M = 2 * SEQ;   // 4096

    char* p = (char*)d_ws;
    ushort_t* xh   = (ushort_t*)p; p += (size_t)M * CDIM * 2;        // 8 MB, reused as yh
    ushort_t* wqh  = (ushort_t*)p; p += (size_t)CDIM * CDIM * 2;     // 2 MB
    ushort_t* wkh  = (ushort_t*)p; p += (size_t)KVDIM * CDIM * 2;    // 1 MB
    ushort_t* wvh  = (ushort_t*)p; p += (size_t)KVDIM * CDIM * 2;    // 1 MB
    ushort_t* wph  = (ushort_t*)p; p += (size_t)CDIM * CDIM * 2;     // 2 MB
    ushort_t* qh   = (ushort_t*)p; p += (size_t)M * CDIM * 2;        // 8 MB
    ushort_t* kh   = (ushort_t*)p; p += (size_t)M * KVDIM * 2;       // 4 MB
    float*    vbuf = (float*)p;    p += (size_t)M * KVDIM * 4;       // 8 MB
    ushort_t* vth  = (ushort_t*)p; p += (size_t)M * KVDIM * 2;       // 4 MB
    ushort_t* yh = xh;   // x no longer needed once qkv GEMM is done

    dim3 blk(256);

    cvt_bf16<<<dim3(7168), blk, 0, stream>>>(
        x, Wq, Wk, Wv, Wproj, xh, wqh, wkh, wvh, wph);

    // fused q/k/v projections: q bf16*SCL2E, k bf16, v fp32
    gemm128db<<<dim3(16, 32), blk, 0, stream>>>(
        xh, CDIM,
        wqh, qh,   CDIM,  3, SCL2E,
        wkh, kh,   KVDIM, 3, 1.0f,
        wvh, vbuf, KVDIM, 0, 1.0f);

    vtrans_kernel<<<dim3(SEQ / 64, 16), blk, 0, stream>>>(vbuf, vth);

    attn4<<<dim3(SEQ / 128, 32), blk, 0, stream>>>(qh, kh, vth, yh);

    gemm128db<<<dim3(8, 32), blk, 0, stream>>>(
        yh, CDIM,
        wph, out, CDIM, 0, 1.0f,
        nullptr, nullptr, 0, 0, 1.0f,
        nullptr, nullptr, 0, 0, 1.0f);
}